// Round 9
// baseline (28340.378 us; speedup 1.0000x reference)
//
#include <hip/hip_runtime.h>
#include <hip/hip_bf16.h>
#include <math.h>

#define NP 16384
#define CI 512
#define CO 512
#define NE 262144
#define MS 8192
#define BN_EPS 1e-5f
#define NCELL 4096

// ---------------------------------------------------------------------------
// GEMM: H[n][o] = sum_k X[n][k]*W[o][k] + b[o]
// ---------------------------------------------------------------------------
__global__ __launch_bounds__(256) void gemm_kernel(const float* __restrict__ X,
                                                   const float* __restrict__ W,
                                                   const float* __restrict__ bias,
                                                   float* __restrict__ H) {
  __shared__ float As[16][65];
  __shared__ float Bs[16][65];
  const int bm = blockIdx.x * 64;
  const int bn = blockIdx.y * 64;
  const int t  = threadIdx.x;
  const int tm = (t >> 4) << 2;
  const int tn = (t & 15) << 2;
  const int lr = t >> 2;
  const int lc = (t & 3) << 2;

  float acc[4][4] = {};

  for (int k0 = 0; k0 < CI; k0 += 16) {
    float4 a = *(const float4*)(X + (size_t)(bm + lr) * CI + k0 + lc);
    float4 b = *(const float4*)(W + (size_t)(bn + lr) * CI + k0 + lc);
    As[lc + 0][lr] = a.x; As[lc + 1][lr] = a.y; As[lc + 2][lr] = a.z; As[lc + 3][lr] = a.w;
    Bs[lc + 0][lr] = b.x; Bs[lc + 1][lr] = b.y; Bs[lc + 2][lr] = b.z; Bs[lc + 3][lr] = b.w;
    __syncthreads();
#pragma unroll
    for (int k = 0; k < 16; ++k) {
      float av[4], bv[4];
#pragma unroll
      for (int i = 0; i < 4; ++i) av[i] = As[k][tm + i];
#pragma unroll
      for (int j = 0; j < 4; ++j) bv[j] = Bs[k][tn + j];
#pragma unroll
      for (int i = 0; i < 4; ++i)
#pragma unroll
        for (int j = 0; j < 4; ++j) acc[i][j] += av[i] * bv[j];
    }
    __syncthreads();
  }
#pragma unroll
  for (int i = 0; i < 4; ++i)
#pragma unroll
    for (int j = 0; j < 4; ++j)
      H[(size_t)(bm + tm + i) * CO + bn + tn + j] = acc[i][j] + bias[bn + tn + j];
}

// ---------------------------------------------------------------------------
// BN
// ---------------------------------------------------------------------------
__global__ __launch_bounds__(256) void bn_stats_kernel(const float* __restrict__ H,
                                                       float* __restrict__ psum,
                                                       float* __restrict__ psq) {
  const int col = blockIdx.x * 256 + threadIdx.x;
  const int r0  = blockIdx.y * 256;
  float s = 0.f, q = 0.f;
  for (int r = r0; r < r0 + 256; ++r) {
    float v = H[(size_t)r * CO + col];
    s += v;
    q += v * v;
  }
  psum[blockIdx.y * CO + col] = s;
  psq [blockIdx.y * CO + col] = q;
}

__global__ __launch_bounds__(512) void bn_final_kernel(const float* __restrict__ psum,
                                                       const float* __restrict__ psq,
                                                       const float* __restrict__ gamma,
                                                       const float* __restrict__ beta,
                                                       float* __restrict__ scale,
                                                       float* __restrict__ shift) {
  const int c = threadIdx.x;
  float s = 0.f, q = 0.f;
  for (int r = 0; r < 64; ++r) {
    s += psum[r * CO + c];
    q += psq [r * CO + c];
  }
  const float inv_n = 1.0f / (float)NP;
  float mu  = s * inv_n;
  float var = q * inv_n - mu * mu;
  float rs  = rsqrtf(var + BN_EPS);
  float a   = rs * gamma[c];
  scale[c] = a;
  shift[c] = beta[c] - mu * a;
}

__global__ __launch_bounds__(256) void bn_relu_kernel(float* __restrict__ H,
                                                      const float* __restrict__ scale,
                                                      const float* __restrict__ shift) {
  __shared__ float sc[CO], sh[CO];
  for (int i = threadIdx.x; i < CO; i += 256) { sc[i] = scale[i]; sh[i] = shift[i]; }
  __syncthreads();
  const int total4 = NP * CO / 4;
  const int stride = gridDim.x * blockDim.x;
  for (int idx = blockIdx.x * blockDim.x + threadIdx.x; idx < total4; idx += stride) {
    float4 v = ((float4*)H)[idx];
    int c = (idx << 2) & (CO - 1);
    v.x = fmaxf(fmaf(v.x, sc[c + 0], sh[c + 0]), 0.f);
    v.y = fmaxf(fmaf(v.y, sc[c + 1], sh[c + 1]), 0.f);
    v.z = fmaxf(fmaf(v.z, sc[c + 2], sh[c + 2]), 0.f);
    v.w = fmaxf(fmaf(v.w, sc[c + 3], sh[c + 3]), 0.f);
    ((float4*)H)[idx] = v;
  }
}

// ---------------------------------------------------------------------------
// Morton-cell counting sort
// ---------------------------------------------------------------------------
__device__ __forceinline__ unsigned p3(unsigned v) {
  v &= 0x3FFu;
  v = (v * 0x00010001u) & 0xFF0000FFu;
  v = (v * 0x00000101u) & 0x0F00F00Fu;
  v = (v * 0x00000011u) & 0xC30C30C3u;
  v = (v * 0x00000005u) & 0x49249249u;
  return v;
}

__global__ __launch_bounds__(256) void cell_kernel(const float* __restrict__ pos,
                                                   int* __restrict__ cid,
                                                   int* __restrict__ cnt) {
  int i = blockIdx.x * 256 + threadIdx.x;
  if (i < NP) {
    int cx = min(15, max(0, (int)(pos[3 * i + 0] * 16.f)));
    int cy = min(15, max(0, (int)(pos[3 * i + 1] * 16.f)));
    int cz = min(15, max(0, (int)(pos[3 * i + 2] * 16.f)));
    int c = (int)(p3(cx) | (p3(cy) << 1) | (p3(cz) << 2));
    cid[i] = c;
    atomicAdd(&cnt[c], 1);
  }
}

__global__ __launch_bounds__(1024) void cellscan_kernel(const int* __restrict__ cnt,
                                                        int* __restrict__ ccur) {
  const int t = threadIdx.x;
  const int base = t * 4;
  int c[4];
  int s = 0;
#pragma unroll
  for (int j = 0; j < 4; ++j) { c[j] = cnt[base + j]; s += c[j]; }
  const int lane = t & 63, wid = t >> 6;
  int incl = s;
#pragma unroll
  for (int off = 1; off < 64; off <<= 1) {
    int v = __shfl_up(incl, off);
    if (lane >= off) incl += v;
  }
  __shared__ int wtot[16];
  if (lane == 63) wtot[wid] = incl;
  __syncthreads();
  if (t < 16) {
    int v = wtot[t];
    int p = v;
#pragma unroll
    for (int off = 1; off < 16; off <<= 1) {
      int u = __shfl_up(p, off);
      if (t >= off) p += u;
    }
    wtot[t] = p - v;
  }
  __syncthreads();
  int off = wtot[wid] + incl - s;
#pragma unroll
  for (int j = 0; j < 4; ++j) { ccur[base + j] = off; off += c[j]; }
}

__global__ __launch_bounds__(256) void cellscatter_kernel(const float* __restrict__ pos,
                                                          const int* __restrict__ cid,
                                                          int* __restrict__ ccur,
                                                          float4* __restrict__ spos) {
  int i = blockIdx.x * 256 + threadIdx.x;
  if (i < NP) {
    int p = atomicAdd(&ccur[cid[i]], 1);
    spos[p] = make_float4(pos[3 * i + 0], pos[3 * i + 1], pos[3 * i + 2],
                          __int_as_float(i));
  }
}

// ---------------------------------------------------------------------------
// FPS: 1024 threads (16 waves). Register state per lane is ONLY dmin[16] +
// scalars (~58 VGPR -> fits the compiler's 64-VGPR target, no spill).
// Point coords are re-read from global spos inside the PRUNED body (idle
// waves read nothing; active waves hit L1/L2). Exchange restructured to
// minimize LDS-pipe pressure: slot write -> barrier -> wave-0-only 16-slot
// reduce -> single float4 broadcast -> barrier -> all read (~60 DS insts vs
// ~190). flags stores moved out of the loop (LDS winlist, epilogue flush).
// dmin update keeps the exact XLA rounding chain; fmin is exact, so skipping
// provably-no-op centers is bit-safe (margin 1e-4 >> fp error). Tie-breaks
// resolve to the first (lowest sorted index) max at every level.
// ---------------------------------------------------------------------------
template <int CTRL>
__device__ __forceinline__ float dpp_max_step(float v) {
  int o = __builtin_amdgcn_update_dpp(__float_as_int(v), __float_as_int(v),
                                      CTRL, 0xf, 0xf, false);
  return fmaxf(v, __int_as_float(o));
}
__device__ __forceinline__ float readlane_f(float v, int lane) {
  return __int_as_float(__builtin_amdgcn_readlane(__float_as_int(v), lane));
}

__global__ __launch_bounds__(1024) void fps_kernel(const float4* __restrict__ spos,
                                                   const float* __restrict__ pos,
                                                   int* __restrict__ flags) {
  const int t = threadIdx.x;
  const int lane = t & 63;
  const int w = t >> 6;      // 0..15

  __shared__ int    sorig[NP];     // sorted -> original index (64 KB)
  __shared__ int    winlist[MS];   // winner sorted indices (32 KB)
  __shared__ float4 slotA[16];     // per-wave (val, x, y, z)
  __shared__ int    slotB[16];     // per-wave winner sorted index
  __shared__ float4 bcast;         // winner (x, y, z, -)

  float dmin[16];
  const float4* sp = spos + (size_t)t * 16;

  // init: bbox/radius of this lane's 16 consecutive Morton points
  float lox, hix, loy, hiy, loz, hiz;
  {
    float4 p0 = sp[0];
    sorig[t * 16] = __float_as_int(p0.w);
    dmin[0] = __builtin_huge_valf();
    lox = hix = p0.x; loy = hiy = p0.y; loz = hiz = p0.z;
#pragma unroll
    for (int k = 1; k < 16; ++k) {
      float4 p = sp[k];
      sorig[t * 16 + k] = __float_as_int(p.w);
      dmin[k] = __builtin_huge_valf();
      lox = fminf(lox, p.x); hix = fmaxf(hix, p.x);
      loy = fminf(loy, p.y); hiy = fmaxf(hiy, p.y);
      loz = fminf(loz, p.z); hiz = fmaxf(hiz, p.z);
    }
  }
  const float cgx = 0.5f * (lox + hix), cgy = 0.5f * (loy + hiy), cgz = 0.5f * (loz + hiz);
  float r2 = 0.f;
#pragma unroll
  for (int k = 0; k < 16; ++k) {
    float4 p = sp[k];
    float dx = p.x - cgx, dy = p.y - cgy, dz = p.z - cgz;
    r2 = fmaxf(r2, dx * dx + dy * dy + dz * dz);
  }
  const float rad = sqrtf(r2) * 1.0001f + 1e-7f;
  float ssq = __builtin_huge_valf();

  // cached wave-winner payload (replayed by idle waves)
  float cwv = -1.f, cwx = 0.f, cwy = 0.f, cwz = 0.f;
  int   cwi = 0;

  for (int i = t; i < MS; i += 1024) winlist[i] = -1;
  float ccx = pos[0], ccy = pos[1], ccz = pos[2];
  if (t == 0) flags[0] = 1;
  __syncthreads();

  for (int it = 1; it < MS; ++it) {
    float dxc = ccx - cgx, dyc = ccy - cgy, dzc = ccz - cgz;
    float d2c = fmaf(dxc, dxc, fmaf(dyc, dyc, dzc * dzc));
    float thr = ssq + rad;
    if (__any(d2c < thr * thr)) {   // wave-uniform prune
      float bv = -1.f, bx = 0.f, by = 0.f, bz = 0.f;
      int bk = 0;
#pragma unroll
      for (int k = 0; k < 16; ++k) {
        float4 p = sp[k];          // L1/L2 resident; only active waves load
        float dx = __fsub_rn(p.x, ccx);
        float dy = __fsub_rn(p.y, ccy);
        float dz = __fsub_rn(p.z, ccz);
        float d  = __fadd_rn(__fadd_rn(__fmul_rn(dx, dx), __fmul_rn(dy, dy)),
                             __fmul_rn(dz, dz));
        float dm = fminf(dmin[k], d);
        dmin[k] = dm;
        if (dm > bv) { bv = dm; bk = k; bx = p.x; by = p.y; bz = p.z; }
      }
      ssq = sqrtf(bv) * 1.0001f;
      // wave argmax: DPP value max, ballot + readlane extraction
      float m = bv;
      m = dpp_max_step<0x111>(m);  // row_shr:1
      m = dpp_max_step<0x112>(m);  // row_shr:2
      m = dpp_max_step<0x114>(m);  // row_shr:4
      m = dpp_max_step<0x118>(m);  // row_shr:8
      m = dpp_max_step<0x142>(m);  // row_bcast:15
      m = dpp_max_step<0x143>(m);  // row_bcast:31
      float wmax = readlane_f(m, 63);
      unsigned long long ball = __ballot(bv == wmax);
      int srcl = (int)__ffsll(ball) - 1;   // lowest lane = lowest sorted idx
      cwi = __builtin_amdgcn_readlane(t * 16 + bk, srcl);
      cwx = readlane_f(bx, srcl);
      cwy = readlane_f(by, srcl);
      cwz = readlane_f(bz, srcl);
      cwv = wmax;
    }
    if (lane == 0) {
      slotA[w] = make_float4(cwv, cwx, cwy, cwz);
      slotB[w] = cwi;
    }
    __syncthreads();

    if (w == 0) {   // wave 0 alone reduces the 16 slots
      const int q = lane & 15;
      float4 sa = slotA[q];
      int    sb = slotB[q];
      float v2 = sa.x;
      int   qi = q;
#pragma unroll
      for (int off = 1; off < 16; off <<= 1) {
        float ov = __shfl_xor(v2, off);
        int   oq = __shfl_xor(qi, off);
        if (ov > v2 || (ov == v2 && oq < qi)) { v2 = ov; qi = oq; }
      }
      int qs = __builtin_amdgcn_readfirstlane(qi);   // winning slot (uniform)
      float nx = readlane_f(sa.x, qs);  // unused, keeps sa live uniformly
      (void)nx;
      float wx = readlane_f(sa.y, qs);
      float wy = readlane_f(sa.z, qs);
      float wz = readlane_f(sa.w, qs);
      int   wi = __builtin_amdgcn_readlane(sb, qs);
      if (lane == 0) {
        bcast = make_float4(wx, wy, wz, 0.f);
        winlist[it] = wi;
      }
    }
    __syncthreads();

    float4 bc = bcast;    // same-address LDS read -> broadcast
    ccx = bc.x; ccy = bc.y; ccz = bc.z;
  }

  // epilogue: flush winner flags (sorted -> original)
  __syncthreads();
  for (int i = t; i < MS; i += 1024) {
    int si = winlist[i];
    if (si >= 0) flags[sorig[si]] = 1;
  }
}

// ---------------------------------------------------------------------------
// Compact flags -> sorted selected original indices
// ---------------------------------------------------------------------------
__global__ __launch_bounds__(1024) void compact_kernel(const int* __restrict__ flags,
                                                       int* __restrict__ sel) {
  const int t = threadIdx.x;
  const int base = t * 16;
  int f[16];
  int cnt = 0;
#pragma unroll
  for (int j = 0; j < 16; ++j) { f[j] = flags[base + j]; cnt += f[j]; }
  const int lane = t & 63, wid = t >> 6;
  int incl = cnt;
#pragma unroll
  for (int off = 1; off < 64; off <<= 1) {
    int v = __shfl_up(incl, off);
    if (lane >= off) incl += v;
  }
  __shared__ int wtot[16];
  if (lane == 63) wtot[wid] = incl;
  __syncthreads();
  if (t < 16) {
    int v = wtot[t];
    int s = v;
#pragma unroll
    for (int off = 1; off < 16; off <<= 1) {
      int u = __shfl_up(s, off);
      if (t >= off) s += u;
    }
    wtot[t] = s - v;
  }
  __syncthreads();
  int off = wtot[wid] + incl - cnt;
#pragma unroll
  for (int j = 0; j < 16; ++j)
    if (f[j]) sel[off++] = base + j;
}

// ---------------------------------------------------------------------------
// Edge CSR by dst
// ---------------------------------------------------------------------------
__global__ __launch_bounds__(256) void edge_count_kernel(const int* __restrict__ edge,
                                                         int* __restrict__ count) {
  const int stride = gridDim.x * blockDim.x;
  for (int e = blockIdx.x * blockDim.x + threadIdx.x; e < NE; e += stride)
    atomicAdd(&count[edge[NE + e]], 1);
}

__global__ __launch_bounds__(1024) void scan_offsets_kernel(const int* __restrict__ count,
                                                            int* __restrict__ offs,
                                                            int* __restrict__ cursor) {
  const int t = threadIdx.x;
  const int base = t * 16;
  int c[16];
  int cnt = 0;
#pragma unroll
  for (int j = 0; j < 16; ++j) { c[j] = count[base + j]; cnt += c[j]; }
  const int lane = t & 63, wid = t >> 6;
  int incl = cnt;
#pragma unroll
  for (int off = 1; off < 64; off <<= 1) {
    int v = __shfl_up(incl, off);
    if (lane >= off) incl += v;
  }
  __shared__ int wtot[16];
  if (lane == 63) wtot[wid] = incl;
  __syncthreads();
  if (t < 16) {
    int v = wtot[t];
    int s = v;
#pragma unroll
    for (int off = 1; off < 16; off <<= 1) {
      int u = __shfl_up(s, off);
      if (t >= off) s += u;
    }
    wtot[t] = s - v;
  }
  __syncthreads();
  int off = wtot[wid] + incl - cnt;
#pragma unroll
  for (int j = 0; j < 16; ++j) {
    offs[base + j] = off;
    cursor[base + j] = off;
    off += c[j];
  }
  if (t == 1023) offs[NP] = off;
}

__global__ __launch_bounds__(256) void edge_scatter_kernel(const int* __restrict__ edge,
                                                           int* __restrict__ cursor,
                                                           int* __restrict__ esrc) {
  const int stride = gridDim.x * blockDim.x;
  for (int e = blockIdx.x * blockDim.x + threadIdx.x; e < NE; e += stride) {
    int p = atomicAdd(&cursor[edge[NE + e]], 1);
    esrc[p] = edge[e];
  }
}

// ---------------------------------------------------------------------------
// Pool + gather
// ---------------------------------------------------------------------------
__global__ __launch_bounds__(256) void pool_kernel(const float* __restrict__ H,
                                                   const int* __restrict__ sel,
                                                   const int* __restrict__ offs,
                                                   const int* __restrict__ esrc,
                                                   float* __restrict__ out) {
  const int m = blockIdx.x;
  const int i = sel[m];
  const int c = threadIdx.x;
  float v0 = H[(size_t)i * CO + c];
  float v1 = H[(size_t)i * CO + c + 256];
  const int s0 = offs[i], s1 = offs[i + 1];
  for (int k = s0; k < s1; ++k) {
    const int s = esrc[k];
    v0 = fmaxf(v0, H[(size_t)s * CO + c]);
    v1 = fmaxf(v1, H[(size_t)s * CO + c + 256]);
  }
  out[(size_t)m * CO + c] = v0;
  out[(size_t)m * CO + c + 256] = v1;
}

__global__ __launch_bounds__(256) void gather_pb_kernel(const float* __restrict__ pos,
                                                        const int* __restrict__ batch,
                                                        const int* __restrict__ sel,
                                                        float* __restrict__ out) {
  const int m = blockIdx.x * blockDim.x + threadIdx.x;
  if (m < MS) {
    const int i = sel[m];
    float* opos = out + (size_t)MS * CO;
    opos[3 * m + 0] = pos[3 * i + 0];
    opos[3 * m + 1] = pos[3 * i + 1];
    opos[3 * m + 2] = pos[3 * i + 2];
    ((int*)out)[(size_t)MS * CO + MS * 3 + m] = batch[i];
  }
}

// ---------------------------------------------------------------------------
extern "C" void kernel_launch(void* const* d_in, const int* in_sizes, int n_in,
                              void* d_out, int out_size, void* d_ws, size_t ws_size,
                              hipStream_t stream) {
  const float* x     = (const float*)d_in[0];
  const float* pos   = (const float*)d_in[1];
  const int*   batch = (const int*)  d_in[2];
  const int*   edge  = (const int*)  d_in[3];
  const float* W     = (const float*)d_in[4];
  const float* bias  = (const float*)d_in[5];
  const float* gamma = (const float*)d_in[6];
  const float* beta  = (const float*)d_in[7];
  float* out = (float*)d_out;

  char* ws = (char*)d_ws;
  size_t off = 0;
  auto alloc = [&](size_t bytes) -> void* {
    void* p = ws + off;
    off += (bytes + 255) & ~(size_t)255;
    return p;
  };
  float*  H      = (float*)alloc((size_t)NP * CO * 4);
  float*  psum   = (float*)alloc(64 * CO * 4);
  float*  psq    = (float*)alloc(64 * CO * 4);
  float*  scale  = (float*)alloc(CO * 4);
  float*  shift  = (float*)alloc(CO * 4);
  int*    flags  = (int*)  alloc(NP * 4);
  int*    sel    = (int*)  alloc(MS * 4);
  int*    count  = (int*)  alloc(NP * 4);
  int*    offs   = (int*)  alloc((NP + 1) * 4);
  int*    cursor = (int*)  alloc(NP * 4);
  int*    esrc   = (int*)  alloc(NE * 4);
  int*    cid    = (int*)  alloc(NP * 4);
  int*    cnt    = (int*)  alloc(NCELL * 4);
  int*    ccur   = (int*)  alloc(NCELL * 4);
  float4* spos   = (float4*)alloc((size_t)NP * 16);
  (void)ws_size;

  hipMemsetAsync(flags, 0, NP * 4, stream);
  hipMemsetAsync(count, 0, NP * 4, stream);
  hipMemsetAsync(cnt,   0, NCELL * 4, stream);

  // spatial sort for FPS pruning
  cell_kernel<<<NP / 256, 256, 0, stream>>>(pos, cid, cnt);
  cellscan_kernel<<<1, 1024, 0, stream>>>(cnt, ccur);
  cellscatter_kernel<<<NP / 256, 256, 0, stream>>>(pos, cid, ccur, spos);
  // FPS
  fps_kernel<<<1, 1024, 0, stream>>>(spos, pos, flags);
  compact_kernel<<<1, 1024, 0, stream>>>(flags, sel);
  // Linear + BN + ReLU
  gemm_kernel<<<dim3(NP / 64, CO / 64), 256, 0, stream>>>(x, W, bias, H);
  bn_stats_kernel<<<dim3(2, 64), 256, 0, stream>>>(H, psum, psq);
  bn_final_kernel<<<1, 512, 0, stream>>>(psum, psq, gamma, beta, scale, shift);
  bn_relu_kernel<<<2048, 256, 0, stream>>>(H, scale, shift);
  // edge CSR by dst
  edge_count_kernel<<<512, 256, 0, stream>>>(edge, count);
  scan_offsets_kernel<<<1, 1024, 0, stream>>>(count, offs, cursor);
  edge_scatter_kernel<<<512, 256, 0, stream>>>(edge, cursor, esrc);
  // pooled features + pos/batch gather
  pool_kernel<<<MS, 256, 0, stream>>>(H, sel, offs, esrc, out);
  gather_pb_kernel<<<MS / 256, 256, 0, stream>>>(pos, batch, sel, out);
}